// Round 2
// baseline (289.021 us; speedup 1.0000x reference)
//
#include <hip/hip_runtime.h>

// SVConv2d: out[n,o,h,w] = sum_{ci,kh,kw} weight[o,ci,kh,kw,h,w] * x[n,ci,h+kh-1,w+kw-1] + bias[o]
// N=8, Cin=Cout=32, K=3, H=W=64. Weight is 151 MB -> HBM-bound on the weight stream.
// Each thread owns one (o,h,2w) output column, accumulating all N=8 batch samples in
// registers so every weight element is fetched exactly once, as a coalesced float2.

#define Nn 8
#define CI 32
#define CO 32
#define Hh 64
#define Ww 64
#define HW 4096  // H*W

__global__ __launch_bounds__(64) void svconv_kernel(
    const float* __restrict__ x, const float* __restrict__ wgt,
    const float* __restrict__ bias, float* __restrict__ out) {
  int t = blockIdx.x * 64 + threadIdx.x;   // 0..65535
  int wb = t & 31;                         // w-block index (2 pixels each)
  int h  = (t >> 5) & 63;
  int o  = t >> 11;                        // 0..31
  int w0 = wb << 1;

  float acc0[Nn], acc1[Nn];
  #pragma unroll
  for (int n = 0; n < Nn; ++n) { acc0[n] = 0.f; acc1[n] = 0.f; }

  // weight plane walk: planes ordered (ci, kh, kw), stride HW; start at (o, ci=0, 0, 0, h, w0)
  const float* wq = wgt + (size_t)(o * CI * 9) * HW + h * Ww + w0;

  // column validity (same padding); clamped indices keep loads in-bounds
  const bool c0 = (w0 >= 1);
  const bool c3 = (w0 + 2 < Ww);
  const int  i0 = c0 ? (w0 - 1) : 0;
  const int  i3 = c3 ? (w0 + 2) : (Ww - 1);

  // unroll 2: keeps 6 independent float2 weight loads in flight for HBM latency hiding
  #pragma unroll 2
  for (int ci = 0; ci < CI; ++ci) {
    #pragma unroll
    for (int kh = 0; kh < 3; ++kh) {
      int  ih = h + kh - 1;
      bool rv = ((unsigned)ih < (unsigned)Hh);
      int  ihc = rv ? ih : 0;
      const float* xr = x + ci * HW + ihc * Ww;

      // three kw weight planes, float2 each (coalesced 512B per wave)
      float2 wv0 = *(const float2*)(wq);
      float2 wv1 = *(const float2*)(wq + HW);
      float2 wv2 = *(const float2*)(wq + 2 * HW);
      wq += 3 * HW;

      #pragma unroll
      for (int n = 0; n < Nn; ++n) {
        const float* xrn = xr + n * (CI * HW);
        float xv0 = (rv && c0) ? xrn[i0]     : 0.f;
        float xv1 = rv         ? xrn[w0]     : 0.f;
        float xv2 = rv         ? xrn[w0 + 1] : 0.f;
        float xv3 = (rv && c3) ? xrn[i3]     : 0.f;
        // out(w0):   kw0*x(w0-1) + kw1*x(w0) + kw2*x(w0+1)
        acc0[n] = fmaf(wv0.x, xv0, acc0[n]);
        acc0[n] = fmaf(wv1.x, xv1, acc0[n]);
        acc0[n] = fmaf(wv2.x, xv2, acc0[n]);
        // out(w0+1): kw0*x(w0) + kw1*x(w0+1) + kw2*x(w0+2)
        acc1[n] = fmaf(wv0.y, xv1, acc1[n]);
        acc1[n] = fmaf(wv1.y, xv2, acc1[n]);
        acc1[n] = fmaf(wv2.y, xv3, acc1[n]);
      }
    }
  }

  float b = bias[o];
  size_t obase = (size_t)o * HW + (size_t)h * Ww + w0;
  #pragma unroll
  for (int n = 0; n < Nn; ++n) {
    float2 r;
    r.x = acc0[n] + b;
    r.y = acc1[n] + b;
    *(float2*)(out + (size_t)n * (CO * HW) + obase) = r;
  }
}

extern "C" void kernel_launch(void* const* d_in, const int* in_sizes, int n_in,
                              void* d_out, int out_size, void* d_ws, size_t ws_size,
                              hipStream_t stream) {
  const float* x    = (const float*)d_in[0];
  const float* wgt  = (const float*)d_in[1];
  const float* bias = (const float*)d_in[2];
  float* out = (float*)d_out;

  // 32 o * 64 h * 32 w-blocks = 65536 threads
  dim3 grid(65536 / 64), block(64);
  svconv_kernel<<<grid, block, 0, stream>>>(x, wgt, bias, out);
}

// Round 3
// 231.360 us; speedup vs baseline: 1.2492x; 1.2492x over previous
//
#include <hip/hip_runtime.h>

// SVConv2d: out[n,o,h,w] = sum_{ci,kh,kw} weight[o,ci,kh,kw,h,w] * x[n,ci,h+kh-1,w+kw-1] + bias[o]
// N=8, Cin=Cout=32, K=3, H=W=64. Weight (151 MB) read exactly once -> HBM-bound.
// Round-2 lesson: 1 wave/SIMD was latency-bound at 1.1 TB/s. Fix: 4-way ci-split
// (one wave per split per block) -> 16 waves/CU, LDS reduction of partials.
// Each thread owns (o,h,2w) for its ci-range, all N=8 in registers; x halo via shfl.

#define Nn 8
#define CI 32
#define CO 32
#define Hh 64
#define Ww 64
#define HW 4096
#define SPLITS 4
#define CIPS 8   // ci per split

__global__ __launch_bounds__(256, 4) void svconv_kernel(
    const float* __restrict__ x, const float* __restrict__ wgt,
    const float* __restrict__ bias, float* __restrict__ out) {
  __shared__ float lds[SPLITS][64][17];  // stride 17: 2-way bank alias only (free)

  const int tid  = threadIdx.x;
  const int s    = tid >> 6;      // ci-split 0..3
  const int lane = tid & 63;
  const int hrow = lane >> 5;     // 2 h-rows per wave
  const int wb   = lane & 31;     // w-pair index
  const int w0   = wb << 1;
  const int o     = blockIdx.x >> 5;
  const int hbase = (blockIdx.x & 31) << 1;
  const int h     = hbase + hrow;

  float acc0[Nn], acc1[Nn];
  #pragma unroll
  for (int n = 0; n < Nn; ++n) { acc0[n] = 0.f; acc1[n] = 0.f; }

  const bool c0 = (wb > 0);    // x[w0-1] in bounds
  const bool c3 = (wb < 31);   // x[w0+2] in bounds

  // weight planes ordered (ci, kh, kw), stride HW
  const float* wq = wgt + ((size_t)(o * CI + s * CIPS) * 9) * HW + h * Ww + w0;

  #pragma unroll 2
  for (int ci8 = 0; ci8 < CIPS; ++ci8) {
    const int ci = s * CIPS + ci8;

    // prefetch this ci's 9 weight float2s (deep in-flight for HBM latency hiding)
    float2 wv[3][3];
    #pragma unroll
    for (int kh = 0; kh < 3; ++kh)
      #pragma unroll
      for (int kw = 0; kw < 3; ++kw)
        wv[kh][kw] = *(const float2*)(wq + (kh * 3 + kw) * HW);
    wq += 9 * HW;

    #pragma unroll
    for (int kh = 0; kh < 3; ++kh) {
      const int  ih = h + kh - 1;
      const bool rv = ((unsigned)ih < (unsigned)Hh);
      const int  ihc = rv ? ih : 0;
      const float* xr = x + ci * HW + ihc * Ww + w0;

      #pragma unroll
      for (int n = 0; n < Nn; ++n) {
        float2 v = *(const float2*)(xr + n * (CI * HW));
        v.x = rv ? v.x : 0.f;
        v.y = rv ? v.y : 0.f;
        // halo columns from neighbor lanes; boundary lanes masked to 0
        float xv0 = __shfl_up(v.y, 1, 64);   // x[w0-1]
        xv0 = c0 ? xv0 : 0.f;
        float xv3 = __shfl_down(v.x, 1, 64); // x[w0+2]
        xv3 = c3 ? xv3 : 0.f;
        acc0[n] = fmaf(wv[kh][0].x, xv0, acc0[n]);
        acc0[n] = fmaf(wv[kh][1].x, v.x, acc0[n]);
        acc0[n] = fmaf(wv[kh][2].x, v.y, acc0[n]);
        acc1[n] = fmaf(wv[kh][0].y, v.x, acc1[n]);
        acc1[n] = fmaf(wv[kh][1].y, v.y, acc1[n]);
        acc1[n] = fmaf(wv[kh][2].y, xv3, acc1[n]);
      }
    }
  }

  // reduce the 4 ci-splits through LDS
  #pragma unroll
  for (int n = 0; n < Nn; ++n) {
    lds[s][lane][2 * n]     = acc0[n];
    lds[s][lane][2 * n + 1] = acc1[n];
  }
  __syncthreads();

  const int p  = tid & 63;   // output pair within block
  const int kq = tid >> 6;   // 4 of the 16 (n,pix) values each
  const float b = bias[o];
  #pragma unroll
  for (int i = 0; i < 4; ++i) {
    const int k = kq * 4 + i;
    const float sum = lds[0][p][k] + lds[1][p][k] + lds[2][p][k] + lds[3][p][k];
    const int n = k >> 1, pix = k & 1;
    out[(size_t)(n * CO + o) * HW + (hbase + (p >> 5)) * Ww + (p & 31) * 2 + pix] = sum + b;
  }
}

extern "C" void kernel_launch(void* const* d_in, const int* in_sizes, int n_in,
                              void* d_out, int out_size, void* d_ws, size_t ws_size,
                              hipStream_t stream) {
  const float* x    = (const float*)d_in[0];
  const float* wgt  = (const float*)d_in[1];
  const float* bias = (const float*)d_in[2];
  float* out = (float*)d_out;

  // 32 o * 32 h-pairs = 1024 blocks of 256 threads (4 waves = 4 ci-splits)
  dim3 grid(1024), block(256);
  svconv_kernel<<<grid, block, 0, stream>>>(x, wgt, bias, out);
}